// Round 13
// baseline (213.676 us; speedup 1.0000x reference)
//
#include <hip/hip_runtime.h>
#include <hip/hip_bf16.h>
#include <math.h>

#define DEV __device__ __forceinline__

typedef float  floatx4 __attribute__((ext_vector_type(4)));
typedef short  bf16x8  __attribute__((ext_vector_type(8)));
typedef short  bf16x4  __attribute__((ext_vector_type(4)));

typedef __attribute__((address_space(1))) void gvoid;
typedef __attribute__((address_space(3))) void lvoid;

static constexpr int Bc = 2, Tc = 2048, Cc = 1024, Hc = 16, Dc = 64;

DEV void gload16(const void* g, void* l) {
    __builtin_amdgcn_global_load_lds((gvoid*)g, (lvoid*)l, 16, 0, 0);
}

// ---------------------------------------------------------------------------
// Fused prep: fp32->bf16 for x / w_qkv / w_out, plus RoPE cos/sin tables.
// ---------------------------------------------------------------------------
__global__ void prep_kernel(const float* __restrict__ xf,
                            const float* __restrict__ wqkvf,
                            const float* __restrict__ woutf,
                            __hip_bfloat16* __restrict__ xb,
                            __hip_bfloat16* __restrict__ wqkvb,
                            __hip_bfloat16* __restrict__ woutb,
                            float* __restrict__ cosT, float* __restrict__ sinT) {
    int gb = blockIdx.x;
    if (gb < 8192) {
        const float* src; __hip_bfloat16* dst; int i;
        if (gb < 4096)      { src = xf;    dst = xb;    i = gb * 256 + threadIdx.x; }
        else if (gb < 7168) { src = wqkvf; dst = wqkvb; i = (gb - 4096) * 256 + threadIdx.x; }
        else                { src = woutf; dst = woutb; i = (gb - 7168) * 256 + threadIdx.x; }
        float4 f = ((const float4*)src)[i];
        union { ushort4 u; __hip_bfloat16 h[4]; } pk;
        pk.h[0] = __float2bfloat16(f.x);
        pk.h[1] = __float2bfloat16(f.y);
        pk.h[2] = __float2bfloat16(f.z);
        pk.h[3] = __float2bfloat16(f.w);
        ((ushort4*)dst)[i] = pk.u;
    } else {
        int i = (gb - 8192) * 256 + threadIdx.x;   // 0..65535
        int t = i >> 5, j = i & 31;
        float invf = powf(10000.0f, -(float)j / 32.0f);
        float f = (float)t * invf;
        cosT[i] = cosf(f);
        sinT[i] = sinf(f);
    }
}

// ---------------------------------------------------------------------------
// GEMM1: qkv = x @ w_qkv^T. 128x128 tile, BK=64, m97 pattern + XOR swizzle.
// Epilogue: bn<2048: RoPE+scatter q (pre-scaled) / k -> (B,H,T,D);
//           bn>=2048: v -> TRANSPOSED (B,H,D,T) via LDS, line-coalesced.
// ---------------------------------------------------------------------------
__global__ __launch_bounds__(256, 2) void gemm_qkv(
    const __hip_bfloat16* __restrict__ A,   // M x K
    const __hip_bfloat16* __restrict__ Bm,  // N x K
    __hip_bfloat16* __restrict__ qb,
    __hip_bfloat16* __restrict__ kb,
    __hip_bfloat16* __restrict__ vb,        // transposed planes [bh][d][t]
    const float* __restrict__ cosT,
    const float* __restrict__ sinT,
    int K)
{
    __shared__ __align__(16) __hip_bfloat16 SM[2 * 128 * 64];   // As | Bs (32KB)
    __hip_bfloat16* const As = SM;
    __hip_bfloat16* const Bs = SM + 128 * 64;

    const int tid  = threadIdx.x;
    const int lane = tid & 63, wave = tid >> 6;
    const int quad = lane >> 4, cidx = lane & 15;
    const int wm = wave & 1, wn = wave >> 1;
    const int bm = blockIdx.x * 128, bn = blockIdx.y * 128;

    floatx4 acc[4][4] = {};

    for (int k0 = 0; k0 < K; k0 += 64) {
#pragma unroll
        for (int it = 0; it < 4; ++it) {
            int idx = tid + it * 256;
            int r = idx >> 3, cs = idx & 7;
            int cg = cs ^ (r & 7);
            gload16(A  + (size_t)(bm + r) * K + k0 + cg * 8, As + idx * 8);
            gload16(Bm + (size_t)(bn + r) * K + k0 + cg * 8, Bs + idx * 8);
        }
        __syncthreads();
#pragma unroll
        for (int ks = 0; ks < 2; ++ks) {
            bf16x8 af[4], bf[4];
#pragma unroll
            for (int mt = 0; mt < 4; ++mt) {
                int r = wm * 64 + mt * 16 + cidx;
                af[mt] = *(const bf16x8*)(As + (r * 8 + ((ks * 4 + quad) ^ (r & 7))) * 8);
            }
#pragma unroll
            for (int nt = 0; nt < 4; ++nt) {
                int r = wn * 64 + nt * 16 + cidx;
                bf[nt] = *(const bf16x8*)(Bs + (r * 8 + ((ks * 4 + quad) ^ (r & 7))) * 8);
            }
#pragma unroll
            for (int mt = 0; mt < 4; ++mt)
#pragma unroll
                for (int nt = 0; nt < 4; ++nt)
                    acc[mt][nt] = __builtin_amdgcn_mfma_f32_16x16x32_bf16(
                        af[mt], bf[nt], acc[mt][nt], 0, 0, 0);
        }
        __syncthreads();
    }

    if (bn >= 2048) {
        // ---- v tile: LDS transpose -> [bh][d][t], line-coalesced stores ----
#pragma unroll
        for (int nt = 0; nt < 4; ++nt) {
            int n_l = wn * 64 + nt * 16 + cidx;
#pragma unroll
            for (int mt = 0; mt < 4; ++mt)
#pragma unroll
                for (int reg = 0; reg < 4; ++reg) {
                    int m_l = wm * 64 + mt * 16 + quad * 4 + reg;
                    SM[n_l * 128 + (((m_l >> 3) ^ (n_l & 15)) * 8) + (m_l & 7)] =
                        __float2bfloat16(acc[mt][nt][reg]);
                }
        }
        __syncthreads();
        {
            int b = bm >> 11, t0 = bm & 2047;
            int c = tid & 15;
#pragma unroll
            for (int it = 0; it < 8; ++it) {
                int row = it * 16 + (tid >> 4);     // d dimension
                int cc = (bn - 2048) + row;
                int h = cc >> 6, d = cc & 63;
                *(uint4*)(vb + ((size_t)(b * Hc + h) * Dc + d) * Tc + t0 + c * 8) =
                    *(const uint4*)(SM + row * 128 + ((c ^ (row & 15)) * 8));
            }
        }
    } else {
        // ---- q / k tiles: RoPE + scatter ----
        const float SL2E = 0.125f * 1.44269504088896f;  // softmax scale * log2(e)
#pragma unroll
        for (int nt = 0; nt < 4; ++nt) {
            int n   = bn + wn * 64 + nt * 16 + cidx;
            int sec = n >> 10;          // 0=q 1=k
            int cc  = n & 1023;
            int h = cc >> 6, d = cc & 63, j = d >> 1;
            __hip_bfloat16* dst = (sec == 0) ? qb : kb;
#pragma unroll
            for (int mt = 0; mt < 4; ++mt) {
#pragma unroll
                for (int reg = 0; reg < 4; ++reg) {
                    int m = bm + wm * 64 + mt * 16 + quad * 4 + reg;
                    int b = m >> 11, t = m & 2047;
                    float v = acc[mt][nt][reg];
                    float p = __shfl_xor(v, 1);
                    float cz = cosT[t * 32 + j];
                    float sz = sinT[t * 32 + j];
                    float o = (d & 1) ? (p * sz + v * cz) : (v * cz - p * sz);
                    if (sec == 0) o *= SL2E;
                    dst[((size_t)(b * Hc + h) * Tc + t) * Dc + d] = __float2bfloat16(o);
                }
            }
        }
    }
}

// ---------------------------------------------------------------------------
// GEMM2: out = ab @ w_out^T, fp32 store. 64x128 tile (512 blocks = 2/CU).
// A (ab) is PLANAR [bh][t][d]: logical k = h*64+d, m = b*2048+t.
// ---------------------------------------------------------------------------
__global__ __launch_bounds__(256, 2) void gemm_out(
    const __hip_bfloat16* __restrict__ A,   // planar [bh][t][d]
    const __hip_bfloat16* __restrict__ Bm,  // 1024 x 1024
    float* __restrict__ Cout)
{
    __shared__ __align__(16) __hip_bfloat16 As[64 * 64];
    __shared__ __align__(16) __hip_bfloat16 Bs[128 * 64];

    const int tid  = threadIdx.x;
    const int lane = tid & 63, wave = tid >> 6;
    const int quad = lane >> 4, cidx = lane & 15;
    const int bm = blockIdx.x * 64, bn = blockIdx.y * 128;
    const int K = 1024;

    floatx4 acc[4][2] = {};

    for (int k0 = 0; k0 < K; k0 += 64) {
        int h = k0 >> 6;
#pragma unroll
        for (int it = 0; it < 2; ++it) {
            int idx = tid + it * 256;        // 0..511
            int r = idx >> 3, cs = idx & 7;
            int cg = cs ^ (r & 7);
            int m = bm + r;
            const __hip_bfloat16* src =
                A + ((size_t)((m >> 11) * 16 + h) * 2048 + (m & 2047)) * 64 + cg * 8;
            gload16(src, As + idx * 8);
        }
#pragma unroll
        for (int it = 0; it < 4; ++it) {
            int idx = tid + it * 256;        // 0..1023
            int r = idx >> 3, cs = idx & 7;
            int cg = cs ^ (r & 7);
            gload16(Bm + (size_t)(bn + r) * K + k0 + cg * 8, Bs + idx * 8);
        }
        __syncthreads();
#pragma unroll
        for (int ks = 0; ks < 2; ++ks) {
            bf16x8 af[4], bf[2];
#pragma unroll
            for (int mt = 0; mt < 4; ++mt) {
                int r = mt * 16 + cidx;
                af[mt] = *(const bf16x8*)(As + (r * 8 + ((ks * 4 + quad) ^ (r & 7))) * 8);
            }
#pragma unroll
            for (int nt = 0; nt < 2; ++nt) {
                int r = wave * 32 + nt * 16 + cidx;
                bf[nt] = *(const bf16x8*)(Bs + (r * 8 + ((ks * 4 + quad) ^ (r & 7))) * 8);
            }
#pragma unroll
            for (int mt = 0; mt < 4; ++mt)
#pragma unroll
                for (int nt = 0; nt < 2; ++nt)
                    acc[mt][nt] = __builtin_amdgcn_mfma_f32_16x16x32_bf16(
                        af[mt], bf[nt], acc[mt][nt], 0, 0, 0);
        }
        __syncthreads();
    }

#pragma unroll
    for (int mt = 0; mt < 4; ++mt)
#pragma unroll
        for (int nt = 0; nt < 2; ++nt) {
            int n = bn + wave * 32 + nt * 16 + cidx;
#pragma unroll
            for (int reg = 0; reg < 4; ++reg) {
                int m = bm + mt * 16 + quad * 4 + reg;
                Cout[(size_t)m * 1024 + n] = acc[mt][nt][reg];
            }
        }
}

// ---------------------------------------------------------------------------
// Causal MFMA flash attention v3:
//  - keys wave-private -> K fragments loaded DIRECTLY global->VGPR (coalesced
//    16-row x 64B reads, L2-local via XCD swizzle) — K never touches LDS.
//  - Vt double-buffered, ONE barrier per k-tile; its vmcnt-drain covers V and
//    K prefetches issued a full tile earlier (true pipelining).
//  - register-direct P into 16x16x16 MFMA (R12), planar output.
//  LDS/block-tile: 32KB (was 80KB). 49KB total -> 3 blocks/CU.
// ---------------------------------------------------------------------------
__global__ __launch_bounds__(256, 3) void attn_kernel(
    const __hip_bfloat16* __restrict__ qb,
    const __hip_bfloat16* __restrict__ kb,
    const __hip_bfloat16* __restrict__ vb,   // [bh][d][t]
    __hip_bfloat16* __restrict__ ob)         // planar [bh][t][d]
{
    __shared__ __align__(16) __hip_bfloat16 Vt[2][64 * 128];  // V^T dbuf / Q / O-red
    __shared__ __align__(16) __hip_bfloat16 Ps[128 * 64];     // O-red scratch
    __shared__ float Ls[4][64];

    const int tid  = threadIdx.x;
    const int lane = tid & 63, wave = tid >> 6;
    const int quad = lane >> 4, cidx = lane & 15;
    const int id = blockIdx.x;
    const int xcd = id & 7, s = id >> 3;
    const int bh = xcd * 4 + (s >> 4);
    const int bx = s & 15;
    const size_t plane = (size_t)bh * Tc * Dc;
    const __hip_bfloat16* Vp = vb + plane;
    const __hip_bfloat16* Kp = kb + plane;

    for (int half = 0; half < 2; ++half) {
        const int qt = half ? bx : 31 - bx;
        const int qbase = qt * 64;
        const int ktmax = (qbase + 63) >> 7;

        // ---- prologue: Q -> Vt[0]; K(0) -> registers ----
#pragma unroll
        for (int it = 0; it < 2; ++it) {
            int idx = tid + it * 256;
            int r = idx >> 3, cs = idx & 7;
            int cg = cs ^ (r & 7);
            gload16(qb + plane + (size_t)(qbase + r) * 64 + cg * 8, &Vt[0][idx * 8]);
        }
        bf16x8 kcur[2][2];
#pragma unroll
        for (int nt2 = 0; nt2 < 2; ++nt2)
#pragma unroll
            for (int ks = 0; ks < 2; ++ks)
                kcur[nt2][ks] = *(const bf16x8*)(
                    Kp + (size_t)(wave * 32 + nt2 * 16 + cidx) * 64 + (ks * 4 + quad) * 8);
        __syncthreads();
        bf16x8 qf[4][2];
#pragma unroll
        for (int mt = 0; mt < 4; ++mt)
#pragma unroll
            for (int ks = 0; ks < 2; ++ks) {
                int r = mt * 16 + cidx;
                qf[mt][ks] = *(const bf16x8*)(&Vt[0][(r * 8 + ((ks * 4 + quad) ^ (r & 7))) * 8]);
            }
        __syncthreads();     // qf read; Vt[0] free
        // issue V(0) -> Vt[0]
#pragma unroll
        for (int it = 0; it < 4; ++it) {
            int idx = tid + it * 256;
            int r = idx >> 4, cs = idx & 15;
            int c = cs ^ (r & 15);
            gload16(Vp + (size_t)r * Tc + c * 8, &Vt[0][idx * 8]);
        }

        floatx4 oaccT[4][4] = {};        // [mt(q-blk)][dt(d-blk)]; row=d, col=q
        float lsum[4] = {0.f, 0.f, 0.f, 0.f};

        for (int kt = 0; kt <= ktmax; ++kt) {
            __syncthreads();   // drains V(kt) (and K prefetch); prev-buf reads done

            // prefetch V(kt+1) -> other buffer, K(kt+1) -> registers
            bf16x8 knxt[2][2];
            if (kt < ktmax) {
                __hip_bfloat16* dstb = &Vt[(kt + 1) & 1][0];
#pragma unroll
                for (int it = 0; it < 4; ++it) {
                    int idx = tid + it * 256;
                    int r = idx >> 4, cs = idx & 15;
                    int c = cs ^ (r & 15);
                    gload16(Vp + (size_t)r * Tc + (kt + 1) * 128 + c * 8, dstb + idx * 8);
                }
#pragma unroll
                for (int nt2 = 0; nt2 < 2; ++nt2)
#pragma unroll
                    for (int ks = 0; ks < 2; ++ks)
                        knxt[nt2][ks] = *(const bf16x8*)(
                            Kp + (size_t)((kt + 1) * 128 + wave * 32 + nt2 * 16 + cidx) * 64
                               + (ks * 4 + quad) * 8);
            }

            // S^T = K Q^T : wave's 32 keys (rows) x 64 q (cols)
            floatx4 sacc[4][2] = {};
#pragma unroll
            for (int ks = 0; ks < 2; ++ks)
#pragma unroll
                for (int mt = 0; mt < 4; ++mt)
#pragma unroll
                    for (int nt2 = 0; nt2 < 2; ++nt2)
                        sacc[mt][nt2] = __builtin_amdgcn_mfma_f32_16x16x32_bf16(
                            kcur[nt2][ks], qf[mt][ks], sacc[mt][nt2], 0, 0, 0);

            // p = 2^s, causal mask; pf stays in registers (B-frag of x16 MFMA)
            const bool domask = (kt == ktmax);
            bf16x4 pf[4][2];
#pragma unroll
            for (int mt = 0; mt < 4; ++mt) {
                int q = qbase + mt * 16 + cidx;
#pragma unroll
                for (int nt2 = 0; nt2 < 2; ++nt2) {
#pragma unroll
                    for (int reg = 0; reg < 4; ++reg) {
                        int key = kt * 128 + wave * 32 + nt2 * 16 + quad * 4 + reg;
                        float p = __builtin_amdgcn_exp2f(sacc[mt][nt2][reg]);
                        if (domask && key > q) p = 0.0f;
                        lsum[mt] += p;
                        __hip_bfloat16 hb = __float2bfloat16(p);
                        pf[mt][nt2][reg] = *(const short*)&hb;
                    }
                }
            }

            // O^T += V^T P^T  (16x16x16, P from registers, V from Vt[kt&1])
            const __hip_bfloat16* vbuf = &Vt[kt & 1][0];
#pragma unroll
            for (int dt = 0; dt < 4; ++dt) {
                int d = dt * 16 + cidx;
#pragma unroll
                for (int ks2 = 0; ks2 < 2; ++ks2) {
                    int chunk = wave * 4 + ks2 * 2 + (quad >> 1);
                    bf16x4 vtf = *(const bf16x4*)(
                        vbuf + (d * 16 + (chunk ^ (d & 15))) * 8 + (quad & 1) * 4);
#pragma unroll
                    for (int mt = 0; mt < 4; ++mt)
                        oaccT[mt][dt] = __builtin_amdgcn_mfma_f32_16x16x16bf16_1k(
                            vtf, pf[mt][ks2], oaccT[mt][dt], 0, 0, 0);
                }
            }
#pragma unroll
            for (int nt2 = 0; nt2 < 2; ++nt2)
#pragma unroll
                for (int ks = 0; ks < 2; ++ks)
                    kcur[nt2][ks] = knxt[nt2][ks];
        }
        __syncthreads();   // all Vt reads done; buffers free for O-red

        // ---- reduce l across quads (lanes sharing cidx) ----
#pragma unroll
        for (int off = 16; off < 64; off <<= 1)
#pragma unroll
            for (int mt = 0; mt < 4; ++mt)
                lsum[mt] += __shfl_xor(lsum[mt], off);
        if (quad == 0)
#pragma unroll
            for (int mt = 0; mt < 4; ++mt)
                Ls[wave][mt * 16 + cidx] = lsum[mt];

        // ---- cross-wave O reduction: waves 1..3 dump to Vt[0]/Vt[1]/Ps ----
        if (wave != 0) {
            float* dstw = (wave == 1) ? (float*)&Vt[0][0]
                        : (wave == 2) ? (float*)&Vt[1][0] : (float*)Ps;
#pragma unroll
            for (int mt = 0; mt < 4; ++mt)
#pragma unroll
                for (int dt = 0; dt < 4; ++dt)
                    ((floatx4*)dstw)[(mt * 4 + dt) * 64 + lane] = oaccT[mt][dt];
        }
        __syncthreads();
        if (wave == 0) {
#pragma unroll
            for (int mt = 0; mt < 4; ++mt)
#pragma unroll
                for (int dt = 0; dt < 4; ++dt) {
                    int i = (mt * 4 + dt) * 64 + lane;
                    oaccT[mt][dt] += ((const floatx4*)&Vt[0][0])[i];
                    oaccT[mt][dt] += ((const floatx4*)&Vt[1][0])[i];
                    oaccT[mt][dt] += ((const floatx4*)Ps)[i];
                }
            // normalize -> bf16 O tile into Ps: row q, 16 granules of 4 d
#pragma unroll
            for (int mt = 0; mt < 4; ++mt) {
                int q = mt * 16 + cidx;
                float lt = Ls[0][q] + Ls[1][q] + Ls[2][q] + Ls[3][q];
                float inv = 1.0f / lt;
#pragma unroll
                for (int dt = 0; dt < 4; ++dt) {
                    bf16x4 o4;
#pragma unroll
                    for (int reg = 0; reg < 4; ++reg) {
                        __hip_bfloat16 hb = __float2bfloat16(oaccT[mt][dt][reg] * inv);
                        o4[reg] = *(const short*)&hb;
                    }
                    int g = dt * 4 + quad;
                    *(bf16x4*)(Ps + q * 64 + (g ^ (q & 12)) * 4) = o4;
                }
            }
        }
        __syncthreads();
        // cooperative planar store: 64 rows x 128B contiguous
#pragma unroll
        for (int i = 0; i < 2; ++i) {
            int c = tid * 2 + i;                 // 0..511 16B chunks
            int row = c >> 3, cp = c & 7;
            *(uint4*)(ob + plane + (size_t)(qbase + row) * 64 + cp * 8) =
                *(const uint4*)(Ps + row * 64 + ((cp * 2) ^ (row & 12)) * 4);
        }
        __syncthreads();   // release buffers before next half
    }
}

// ---------------------------------------------------------------------------
extern "C" void kernel_launch(void* const* d_in, const int* in_sizes, int n_in,
                              void* d_out, int out_size, void* d_ws, size_t ws_size,
                              hipStream_t stream) {
    const float* xf = nullptr; const float* wqkvf = nullptr; const float* woutf = nullptr;
    for (int i = 0; i < n_in; ++i) {
        if      (in_sizes[i] == 2 * 2048 * 1024) xf    = (const float*)d_in[i];
        else if (in_sizes[i] == 3 * 1024 * 1024) wqkvf = (const float*)d_in[i];
        else if (in_sizes[i] == 1024 * 1024)     woutf = (const float*)d_in[i];
    }
    float* out = (float*)d_out;   // fp32 output (reference output dtype)

    char* ws = (char*)d_ws;
    const size_t MB = 1024 * 1024;
    __hip_bfloat16* qb    = (__hip_bfloat16*)(ws);
    __hip_bfloat16* kb    = (__hip_bfloat16*)(ws + 8  * MB);
    __hip_bfloat16* vb    = (__hip_bfloat16*)(ws + 16 * MB);   // transposed planes
    __hip_bfloat16* ab    = (__hip_bfloat16*)(ws + 24 * MB);   // planar [bh][t][d]
    float* cosT           = (float*)(ws + 32 * MB);
    float* sinT           = (float*)(ws + 32 * MB + 256 * 1024);
    __hip_bfloat16* xb    = (__hip_bfloat16*)(ws + 33 * MB);
    __hip_bfloat16* wqkvb = (__hip_bfloat16*)(ws + 41 * MB);
    __hip_bfloat16* woutb = (__hip_bfloat16*)(ws + 47 * MB);

    prep_kernel<<<dim3(8448), dim3(256), 0, stream>>>(
        xf, wqkvf, woutf, xb, wqkvb, woutb, cosT, sinT);

    // qkv projection + RoPE (+q pre-scale) + head scatter (v transposed via LDS)
    gemm_qkv<<<dim3(32, 24), dim3(256), 0, stream>>>(
        xb, wqkvb, qb, kb, vb, cosT, sinT, 1024);
    // causal flash attention -> ab planar (B,H,T,D) bf16
    attn_kernel<<<dim3(512), dim3(256), 0, stream>>>(qb, kb, vb, ab);
    // output projection (planar A), fp32 store to d_out
    gemm_out<<<dim3(64, 8), dim3(256), 0, stream>>>(ab, woutb, out);
}

// Round 14
// 168.860 us; speedup vs baseline: 1.2654x; 1.2654x over previous
//
#include <hip/hip_runtime.h>
#include <hip/hip_bf16.h>
#include <math.h>

#define DEV __device__ __forceinline__

typedef float  floatx4 __attribute__((ext_vector_type(4)));
typedef short  bf16x8  __attribute__((ext_vector_type(8)));
typedef short  bf16x4  __attribute__((ext_vector_type(4)));

typedef __attribute__((address_space(1))) void gvoid;
typedef __attribute__((address_space(3))) void lvoid;

static constexpr int Bc = 2, Tc = 2048, Cc = 1024, Hc = 16, Dc = 64;

DEV void gload16(const void* g, void* l) {
    __builtin_amdgcn_global_load_lds((gvoid*)g, (lvoid*)l, 16, 0, 0);
}

// ---------------------------------------------------------------------------
// Fused prep: fp32->bf16 for x / w_qkv / w_out, plus RoPE cos/sin tables.
// ---------------------------------------------------------------------------
__global__ void prep_kernel(const float* __restrict__ xf,
                            const float* __restrict__ wqkvf,
                            const float* __restrict__ woutf,
                            __hip_bfloat16* __restrict__ xb,
                            __hip_bfloat16* __restrict__ wqkvb,
                            __hip_bfloat16* __restrict__ woutb,
                            float* __restrict__ cosT, float* __restrict__ sinT) {
    int gb = blockIdx.x;
    if (gb < 8192) {
        const float* src; __hip_bfloat16* dst; int i;
        if (gb < 4096)      { src = xf;    dst = xb;    i = gb * 256 + threadIdx.x; }
        else if (gb < 7168) { src = wqkvf; dst = wqkvb; i = (gb - 4096) * 256 + threadIdx.x; }
        else                { src = woutf; dst = woutb; i = (gb - 7168) * 256 + threadIdx.x; }
        float4 f = ((const float4*)src)[i];
        union { ushort4 u; __hip_bfloat16 h[4]; } pk;
        pk.h[0] = __float2bfloat16(f.x);
        pk.h[1] = __float2bfloat16(f.y);
        pk.h[2] = __float2bfloat16(f.z);
        pk.h[3] = __float2bfloat16(f.w);
        ((ushort4*)dst)[i] = pk.u;
    } else {
        int i = (gb - 8192) * 256 + threadIdx.x;   // 0..65535
        int t = i >> 5, j = i & 31;
        float invf = powf(10000.0f, -(float)j / 32.0f);
        float f = (float)t * invf;
        cosT[i] = cosf(f);
        sinT[i] = sinf(f);
    }
}

// ---------------------------------------------------------------------------
// GEMM1: qkv = x @ w_qkv^T. 128x128 tile, BK=64, m97 pattern + XOR swizzle.
// Epilogue: bn<2048: RoPE+scatter q (pre-scaled) / k -> (B,H,T,D);
//           bn>=2048: v -> TRANSPOSED (B,H,D,T) via LDS, line-coalesced.
// ---------------------------------------------------------------------------
__global__ __launch_bounds__(256, 2) void gemm_qkv(
    const __hip_bfloat16* __restrict__ A,   // M x K
    const __hip_bfloat16* __restrict__ Bm,  // N x K
    __hip_bfloat16* __restrict__ qb,
    __hip_bfloat16* __restrict__ kb,
    __hip_bfloat16* __restrict__ vb,        // transposed planes [bh][d][t]
    const float* __restrict__ cosT,
    const float* __restrict__ sinT,
    int K)
{
    __shared__ __align__(16) __hip_bfloat16 SM[2 * 128 * 64];   // As | Bs (32KB)
    __hip_bfloat16* const As = SM;
    __hip_bfloat16* const Bs = SM + 128 * 64;

    const int tid  = threadIdx.x;
    const int lane = tid & 63, wave = tid >> 6;
    const int quad = lane >> 4, cidx = lane & 15;
    const int wm = wave & 1, wn = wave >> 1;
    const int bm = blockIdx.x * 128, bn = blockIdx.y * 128;

    floatx4 acc[4][4] = {};

    for (int k0 = 0; k0 < K; k0 += 64) {
#pragma unroll
        for (int it = 0; it < 4; ++it) {
            int idx = tid + it * 256;
            int r = idx >> 3, cs = idx & 7;
            int cg = cs ^ (r & 7);
            gload16(A  + (size_t)(bm + r) * K + k0 + cg * 8, As + idx * 8);
            gload16(Bm + (size_t)(bn + r) * K + k0 + cg * 8, Bs + idx * 8);
        }
        __syncthreads();
#pragma unroll
        for (int ks = 0; ks < 2; ++ks) {
            bf16x8 af[4], bf[4];
#pragma unroll
            for (int mt = 0; mt < 4; ++mt) {
                int r = wm * 64 + mt * 16 + cidx;
                af[mt] = *(const bf16x8*)(As + (r * 8 + ((ks * 4 + quad) ^ (r & 7))) * 8);
            }
#pragma unroll
            for (int nt = 0; nt < 4; ++nt) {
                int r = wn * 64 + nt * 16 + cidx;
                bf[nt] = *(const bf16x8*)(Bs + (r * 8 + ((ks * 4 + quad) ^ (r & 7))) * 8);
            }
#pragma unroll
            for (int mt = 0; mt < 4; ++mt)
#pragma unroll
                for (int nt = 0; nt < 4; ++nt)
                    acc[mt][nt] = __builtin_amdgcn_mfma_f32_16x16x32_bf16(
                        af[mt], bf[nt], acc[mt][nt], 0, 0, 0);
        }
        __syncthreads();
    }

    if (bn >= 2048) {
        // ---- v tile: LDS transpose -> [bh][d][t], line-coalesced stores ----
#pragma unroll
        for (int nt = 0; nt < 4; ++nt) {
            int n_l = wn * 64 + nt * 16 + cidx;
#pragma unroll
            for (int mt = 0; mt < 4; ++mt)
#pragma unroll
                for (int reg = 0; reg < 4; ++reg) {
                    int m_l = wm * 64 + mt * 16 + quad * 4 + reg;
                    SM[n_l * 128 + (((m_l >> 3) ^ (n_l & 15)) * 8) + (m_l & 7)] =
                        __float2bfloat16(acc[mt][nt][reg]);
                }
        }
        __syncthreads();
        {
            int b = bm >> 11, t0 = bm & 2047;
            int c = tid & 15;
#pragma unroll
            for (int it = 0; it < 8; ++it) {
                int row = it * 16 + (tid >> 4);     // d dimension
                int cc = (bn - 2048) + row;
                int h = cc >> 6, d = cc & 63;
                *(uint4*)(vb + ((size_t)(b * Hc + h) * Dc + d) * Tc + t0 + c * 8) =
                    *(const uint4*)(SM + row * 128 + ((c ^ (row & 15)) * 8));
            }
        }
    } else {
        // ---- q / k tiles: RoPE + scatter ----
        const float SL2E = 0.125f * 1.44269504088896f;  // softmax scale * log2(e)
#pragma unroll
        for (int nt = 0; nt < 4; ++nt) {
            int n   = bn + wn * 64 + nt * 16 + cidx;
            int sec = n >> 10;          // 0=q 1=k
            int cc  = n & 1023;
            int h = cc >> 6, d = cc & 63, j = d >> 1;
            __hip_bfloat16* dst = (sec == 0) ? qb : kb;
#pragma unroll
            for (int mt = 0; mt < 4; ++mt) {
#pragma unroll
                for (int reg = 0; reg < 4; ++reg) {
                    int m = bm + wm * 64 + mt * 16 + quad * 4 + reg;
                    int b = m >> 11, t = m & 2047;
                    float v = acc[mt][nt][reg];
                    float p = __shfl_xor(v, 1);
                    float cz = cosT[t * 32 + j];
                    float sz = sinT[t * 32 + j];
                    float o = (d & 1) ? (p * sz + v * cz) : (v * cz - p * sz);
                    if (sec == 0) o *= SL2E;
                    dst[((size_t)(b * Hc + h) * Tc + t) * Dc + d] = __float2bfloat16(o);
                }
            }
        }
    }
}

// ---------------------------------------------------------------------------
// GEMM2: out = ab @ w_out^T, fp32 store. 64x128 tile (512 blocks = 2/CU).
// A (ab) is PLANAR [bh][t][d]: logical k = h*64+d, m = b*2048+t.
// ---------------------------------------------------------------------------
__global__ __launch_bounds__(256, 2) void gemm_out(
    const __hip_bfloat16* __restrict__ A,   // planar [bh][t][d]
    const __hip_bfloat16* __restrict__ Bm,  // 1024 x 1024
    float* __restrict__ Cout)
{
    __shared__ __align__(16) __hip_bfloat16 As[64 * 64];
    __shared__ __align__(16) __hip_bfloat16 Bs[128 * 64];

    const int tid  = threadIdx.x;
    const int lane = tid & 63, wave = tid >> 6;
    const int quad = lane >> 4, cidx = lane & 15;
    const int bm = blockIdx.x * 64, bn = blockIdx.y * 128;
    const int K = 1024;

    floatx4 acc[4][2] = {};

    for (int k0 = 0; k0 < K; k0 += 64) {
        int h = k0 >> 6;
#pragma unroll
        for (int it = 0; it < 2; ++it) {
            int idx = tid + it * 256;        // 0..511
            int r = idx >> 3, cs = idx & 7;
            int cg = cs ^ (r & 7);
            int m = bm + r;
            const __hip_bfloat16* src =
                A + ((size_t)((m >> 11) * 16 + h) * 2048 + (m & 2047)) * 64 + cg * 8;
            gload16(src, As + idx * 8);
        }
#pragma unroll
        for (int it = 0; it < 4; ++it) {
            int idx = tid + it * 256;        // 0..1023
            int r = idx >> 3, cs = idx & 7;
            int cg = cs ^ (r & 7);
            gload16(Bm + (size_t)(bn + r) * K + k0 + cg * 8, Bs + idx * 8);
        }
        __syncthreads();
#pragma unroll
        for (int ks = 0; ks < 2; ++ks) {
            bf16x8 af[4], bf[2];
#pragma unroll
            for (int mt = 0; mt < 4; ++mt) {
                int r = mt * 16 + cidx;
                af[mt] = *(const bf16x8*)(As + (r * 8 + ((ks * 4 + quad) ^ (r & 7))) * 8);
            }
#pragma unroll
            for (int nt = 0; nt < 2; ++nt) {
                int r = wave * 32 + nt * 16 + cidx;
                bf[nt] = *(const bf16x8*)(Bs + (r * 8 + ((ks * 4 + quad) ^ (r & 7))) * 8);
            }
#pragma unroll
            for (int mt = 0; mt < 4; ++mt)
#pragma unroll
                for (int nt = 0; nt < 2; ++nt)
                    acc[mt][nt] = __builtin_amdgcn_mfma_f32_16x16x32_bf16(
                        af[mt], bf[nt], acc[mt][nt], 0, 0, 0);
        }
        __syncthreads();
    }

#pragma unroll
    for (int mt = 0; mt < 4; ++mt)
#pragma unroll
        for (int nt = 0; nt < 2; ++nt) {
            int n = bn + wave * 32 + nt * 16 + cidx;
#pragma unroll
            for (int reg = 0; reg < 4; ++reg) {
                int m = bm + mt * 16 + quad * 4 + reg;
                Cout[(size_t)m * 1024 + n] = acc[mt][nt][reg];
            }
        }
}

// ---------------------------------------------------------------------------
// Causal MFMA flash attention v3b (R12 base + transient direct-K):
//  - keys wave-private -> K fragments loaded global->VGPR INSIDE the loop,
//    right before use (transient: no register blow-up, no spills). K loads
//    issued BEFORE the V gload16s so their waitcnt doesn't drain V.
//  - single Vt buffer, two barriers/tile (A drains V under QK+softmax;
//    B drains nothing). Register-direct P into 16x16x16 MFMA. Planar output.
//  LDS traffic/tile: 32KB (R12: 64KB).
// ---------------------------------------------------------------------------
__global__ __launch_bounds__(256, 2) void attn_kernel(
    const __hip_bfloat16* __restrict__ qb,
    const __hip_bfloat16* __restrict__ kb,
    const __hip_bfloat16* __restrict__ vb,   // [bh][d][t]
    __hip_bfloat16* __restrict__ ob)         // planar [bh][t][d]
{
    __shared__ __align__(16) __hip_bfloat16 Ks[128 * 64];    // Q staging / O-red only
    __shared__ __align__(16) __hip_bfloat16 Vt[64 * 128];    // V^T tile / O-red
    __shared__ __align__(16) __hip_bfloat16 Ps[128 * 64];    // O-red scratch
    __shared__ float Ls[4][64];

    const int tid  = threadIdx.x;
    const int lane = tid & 63, wave = tid >> 6;
    const int quad = lane >> 4, cidx = lane & 15;
    const int id = blockIdx.x;
    const int xcd = id & 7, s = id >> 3;
    const int bh = xcd * 4 + (s >> 4);
    const int bx = s & 15;
    const size_t plane = (size_t)bh * Tc * Dc;
    const __hip_bfloat16* Vp = vb + plane;
    const __hip_bfloat16* Kp = kb + plane;

    for (int half = 0; half < 2; ++half) {
        const int qt = half ? bx : 31 - bx;
        const int qbase = qt * 64;
        const int ktmax = (qbase + 63) >> 7;

        // ---- prologue: stage Q into Ks, hoist qf ----
#pragma unroll
        for (int it = 0; it < 2; ++it) {
            int idx = tid + it * 256;
            int r = idx >> 3, cs = idx & 7;
            int cg = cs ^ (r & 7);
            gload16(qb + plane + (size_t)(qbase + r) * 64 + cg * 8, Ks + idx * 8);
        }
        __syncthreads();
        bf16x8 qf[4][2];
#pragma unroll
        for (int mt = 0; mt < 4; ++mt)
#pragma unroll
            for (int ks = 0; ks < 2; ++ks) {
                int r = mt * 16 + cidx;
                qf[mt][ks] = *(const bf16x8*)(Ks + (r * 8 + ((ks * 4 + quad) ^ (r & 7))) * 8);
            }
        __syncthreads();

        floatx4 oaccT[4][4] = {};        // [mt(q-blk)][dt(d-blk)]; row=d, col=q
        float lsum[4] = {0.f, 0.f, 0.f, 0.f};

        for (int kt = 0; kt <= ktmax; ++kt) {
            // K fragments direct from global (issued FIRST; transient regs)
            bf16x8 kcur[2][2];
#pragma unroll
            for (int nt2 = 0; nt2 < 2; ++nt2)
#pragma unroll
                for (int ks = 0; ks < 2; ++ks)
                    kcur[nt2][ks] = *(const bf16x8*)(
                        Kp + (size_t)(kt * 128 + wave * 32 + nt2 * 16 + cidx) * 64
                           + (ks * 4 + quad) * 8);

            // issue V(kt) -> Vt (drains at barrier A, under QK+softmax)
#pragma unroll
            for (int it = 0; it < 4; ++it) {
                int idx = tid + it * 256;
                int r = idx >> 4, cs = idx & 15;
                int c = cs ^ (r & 15);
                gload16(Vp + (size_t)r * Tc + kt * 128 + c * 8, Vt + idx * 8);
            }

            // S^T = K Q^T : wave's 32 keys (rows) x 64 q (cols)
            floatx4 sacc[4][2] = {};
#pragma unroll
            for (int ks = 0; ks < 2; ++ks)
#pragma unroll
                for (int mt = 0; mt < 4; ++mt)
#pragma unroll
                    for (int nt2 = 0; nt2 < 2; ++nt2)
                        sacc[mt][nt2] = __builtin_amdgcn_mfma_f32_16x16x32_bf16(
                            kcur[nt2][ks], qf[mt][ks], sacc[mt][nt2], 0, 0, 0);

            // p = 2^s, causal mask; pf stays in registers (B-frag of x16 MFMA)
            const bool domask = (kt == ktmax);
            bf16x4 pf[4][2];
#pragma unroll
            for (int mt = 0; mt < 4; ++mt) {
                int q = qbase + mt * 16 + cidx;
#pragma unroll
                for (int nt2 = 0; nt2 < 2; ++nt2) {
#pragma unroll
                    for (int reg = 0; reg < 4; ++reg) {
                        int key = kt * 128 + wave * 32 + nt2 * 16 + quad * 4 + reg;
                        float p = __builtin_amdgcn_exp2f(sacc[mt][nt2][reg]);
                        if (domask && key > q) p = 0.0f;
                        lsum[mt] += p;
                        __hip_bfloat16 hb = __float2bfloat16(p);
                        pf[mt][nt2][reg] = *(const short*)&hb;
                    }
                }
            }

            __syncthreads();   // barrier A: V(kt) drained for all waves

            // O^T += V^T P^T  (16x16x16, P from registers)
#pragma unroll
            for (int dt = 0; dt < 4; ++dt) {
                int d = dt * 16 + cidx;
#pragma unroll
                for (int ks2 = 0; ks2 < 2; ++ks2) {
                    int chunk = wave * 4 + ks2 * 2 + (quad >> 1);
                    bf16x4 vtf = *(const bf16x4*)(
                        Vt + (d * 16 + (chunk ^ (d & 15))) * 8 + (quad & 1) * 4);
#pragma unroll
                    for (int mt = 0; mt < 4; ++mt)
                        oaccT[mt][dt] = __builtin_amdgcn_mfma_f32_16x16x16bf16_1k(
                            vtf, pf[mt][ks2], oaccT[mt][dt], 0, 0, 0);
                }
            }
            __syncthreads();   // barrier B: Vt reads done; free for next V
        }

        // ---- reduce l across quads (lanes sharing cidx) ----
#pragma unroll
        for (int off = 16; off < 64; off <<= 1)
#pragma unroll
            for (int mt = 0; mt < 4; ++mt)
                lsum[mt] += __shfl_xor(lsum[mt], off);
        if (quad == 0)
#pragma unroll
            for (int mt = 0; mt < 4; ++mt)
                Ls[wave][mt * 16 + cidx] = lsum[mt];

        // ---- cross-wave O reduction: waves 1..3 dump to Ks/Vt/Ps ----
        if (wave != 0) {
            float* dstw = (wave == 1) ? (float*)Ks : (wave == 2) ? (float*)Vt : (float*)Ps;
#pragma unroll
            for (int mt = 0; mt < 4; ++mt)
#pragma unroll
                for (int dt = 0; dt < 4; ++dt)
                    ((floatx4*)dstw)[(mt * 4 + dt) * 64 + lane] = oaccT[mt][dt];
        }
        __syncthreads();
        if (wave == 0) {
#pragma unroll
            for (int mt = 0; mt < 4; ++mt)
#pragma unroll
                for (int dt = 0; dt < 4; ++dt) {
                    int i = (mt * 4 + dt) * 64 + lane;
                    oaccT[mt][dt] += ((const floatx4*)Ks)[i];
                    oaccT[mt][dt] += ((const floatx4*)Vt)[i];
                    oaccT[mt][dt] += ((const floatx4*)Ps)[i];
                }
            // normalize -> bf16 O tile into Ps: row q, 16 granules of 4 d
#pragma unroll
            for (int mt = 0; mt < 4; ++mt) {
                int q = mt * 16 + cidx;
                float lt = Ls[0][q] + Ls[1][q] + Ls[2][q] + Ls[3][q];
                float inv = 1.0f / lt;
#pragma unroll
                for (int dt = 0; dt < 4; ++dt) {
                    bf16x4 o4;
#pragma unroll
                    for (int reg = 0; reg < 4; ++reg) {
                        __hip_bfloat16 hb = __float2bfloat16(oaccT[mt][dt][reg] * inv);
                        o4[reg] = *(const short*)&hb;
                    }
                    int g = dt * 4 + quad;
                    *(bf16x4*)(Ps + q * 64 + (g ^ (q & 12)) * 4) = o4;
                }
            }
        }
        __syncthreads();
        // cooperative planar store: 64 rows x 128B contiguous
#pragma unroll
        for (int i = 0; i < 2; ++i) {
            int c = tid * 2 + i;                 // 0..511 16B chunks
            int row = c >> 3, cp = c & 7;
            *(uint4*)(ob + plane + (size_t)(qbase + row) * 64 + cp * 8) =
                *(const uint4*)(Ps + row * 64 + ((cp * 2) ^ (row & 12)) * 4);
        }
        __syncthreads();   // release buffers before next half
    }
}

// ---------------------------------------------------------------------------
extern "C" void kernel_launch(void* const* d_in, const int* in_sizes, int n_in,
                              void* d_out, int out_size, void* d_ws, size_t ws_size,
                              hipStream_t stream) {
    const float* xf = nullptr; const float* wqkvf = nullptr; const float* woutf = nullptr;
    for (int i = 0; i < n_in; ++i) {
        if      (in_sizes[i] == 2 * 2048 * 1024) xf    = (const float*)d_in[i];
        else if (in_sizes[i] == 3 * 1024 * 1024) wqkvf = (const float*)d_in[i];
        else if (in_sizes[i] == 1024 * 1024)     woutf = (const float*)d_in[i];
    }
    float* out = (float*)d_out;   // fp32 output (reference output dtype)

    char* ws = (char*)d_ws;
    const size_t MB = 1024 * 1024;
    __hip_bfloat16* qb    = (__hip_bfloat16*)(ws);
    __hip_bfloat16* kb    = (__hip_bfloat16*)(ws + 8  * MB);
    __hip_bfloat16* vb    = (__hip_bfloat16*)(ws + 16 * MB);   // transposed planes
    __hip_bfloat16* ab    = (__hip_bfloat16*)(ws + 24 * MB);   // planar [bh][t][d]
    float* cosT           = (float*)(ws + 32 * MB);
    float* sinT           = (float*)(ws + 32 * MB + 256 * 1024);
    __hip_bfloat16* xb    = (__hip_bfloat16*)(ws + 33 * MB);
    __hip_bfloat16* wqkvb = (__hip_bfloat16*)(ws + 41 * MB);
    __hip_bfloat16* woutb = (__hip_bfloat16*)(ws + 47 * MB);

    prep_kernel<<<dim3(8448), dim3(256), 0, stream>>>(
        xf, wqkvf, woutf, xb, wqkvb, woutb, cosT, sinT);

    // qkv projection + RoPE (+q pre-scale) + head scatter (v transposed via LDS)
    gemm_qkv<<<dim3(32, 24), dim3(256), 0, stream>>>(
        xb, wqkvb, qb, kb, vb, cosT, sinT, 1024);
    // causal flash attention -> ab planar (B,H,T,D) bf16
    attn_kernel<<<dim3(512), dim3(256), 0, stream>>>(qb, kb, vb, ab);
    // output projection (planar A), fp32 store to d_out
    gemm_out<<<dim3(64, 8), dim3(256), 0, stream>>>(ab, woutb, out);
}